// Round 5
// baseline (1047.913 us; speedup 1.0000x reference)
//
#include <hip/hip_runtime.h>
#include <hip/hip_bf16.h>
#include <cstdint>
#include <cstddef>

typedef __attribute__((ext_vector_type(8))) short short8v;
typedef __attribute__((ext_vector_type(4))) float f32x4;

__device__ __forceinline__ short f2bf(float f) {
    union { float f; unsigned u; } c; c.f = f;
    unsigned r = c.u + 0x7FFFu + ((c.u >> 16) & 1u);
    return (short)(r >> 16);
}

__device__ __forceinline__ float bf2f(ushort u) {
    union { unsigned u; float f; } c; c.u = ((unsigned)u) << 16;
    return c.f;
}

__device__ __forceinline__ void load_lds_16B(const void* g, void* l) {
    __builtin_amdgcn_global_load_lds(
        (const __attribute__((address_space(1))) void*)g,
        (__attribute__((address_space(3))) void*)l, 16, 0, 0);
}

// ---------------- fused fp32 -> bf16 convert of all 4 inputs (+ accum zero) ----------------
__global__ __launch_bounds__(256)
void cvt4_kernel(const float* __restrict__ s0, const float* __restrict__ s1,
                 const float* __restrict__ s2, const float* __restrict__ s3,
                 ushort* __restrict__ dst, double* __restrict__ accum,
                 size_t c0, size_t c1, size_t c2, size_t c3)
{
    if (blockIdx.x == 0 && threadIdx.x == 0) { accum[0] = 0.0; accum[1] = 0.0; }
    size_t stride = (size_t)gridDim.x * blockDim.x;
    for (size_t i = (size_t)blockIdx.x * blockDim.x + threadIdx.x; i < c3; i += stride) {
        const float* src; size_t off;
        if (i < c0)      { src = s0; off = i; }
        else if (i < c1) { src = s1; off = i - c0; }
        else if (i < c2) { src = s2; off = i - c1; }
        else             { src = s3; off = i - c2; }
        const float4* p = reinterpret_cast<const float4*>(src + off * 8);
        float4 a = p[0], b = p[1];
        short8v o = { f2bf(a.x), f2bf(a.y), f2bf(a.z), f2bf(a.w),
                      f2bf(b.x), f2bf(b.y), f2bf(b.z), f2bf(b.w) };
        *reinterpret_cast<short8v*>(dst + i * 8) = o;
    }
}

// ---------------- 256x256 8-phase bf16 GEMM (T1+T2+T3+T4+T5), bf16 C ----------------
// Structure unchanged from round 4 (verified race-free, MfmaUtil ~52%).
// Epilogue transpose-store now XOR-swizzled: physical col16 = col16 ^ ((row>>2&3)<<1)
// -> the 4 lane-quads (which differ in row>>2 by 1) write disjoint 16B-block sets;
// read side applies the same XOR per row (32 distinct blocks per row: conflict-free).

#define SEG_A0 0
#define SEG_A1 16384
#define SEG_B0 32768
#define SEG_B1 49152

#define READ_B_ALL(bseg) do {                                                  \
    _Pragma("unroll")                                                          \
    for (int nf = 0; nf < 4; ++nf) {                                           \
        const int rb = (bseg) + brow + nf * 1024;                              \
        bfr[nf][0] = *(const short8v*)&sh[rb + c16a];                          \
        bfr[nf][1] = *(const short8v*)&sh[rb + c16b];                          \
    }                                                                          \
} while (0)

#define READ_A2(aseg, mfb) do {                                                \
    _Pragma("unroll")                                                          \
    for (int d = 0; d < 2; ++d) {                                              \
        const int ra = (aseg) + arow + ((mfb) + d) * 1024;                     \
        af[d][0] = *(const short8v*)&sh[ra + c16a];                            \
        af[d][1] = *(const short8v*)&sh[ra + c16b];                            \
    }                                                                          \
} while (0)

#define MFMA16(mfb) do {                                                       \
    __builtin_amdgcn_s_setprio(1);                                             \
    _Pragma("unroll")                                                          \
    for (int d = 0; d < 2; ++d) {                                              \
        _Pragma("unroll")                                                      \
        for (int nf = 0; nf < 4; ++nf) {                                       \
            acc[(mfb)+d][nf] = __builtin_amdgcn_mfma_f32_16x16x32_bf16(        \
                af[d][0], bfr[nf][0], acc[(mfb)+d][nf], 0, 0, 0);              \
            acc[(mfb)+d][nf] = __builtin_amdgcn_mfma_f32_16x16x32_bf16(        \
                af[d][1], bfr[nf][1], acc[(mfb)+d][nf], 0, 0, 0);              \
        }                                                                      \
    }                                                                          \
    __builtin_amdgcn_s_setprio(0);                                             \
} while (0)

#define BAR() __builtin_amdgcn_s_barrier()
#define VMCNT4() asm volatile("s_waitcnt vmcnt(4)" ::: "memory")
#define VMCNT0() asm volatile("s_waitcnt vmcnt(0)" ::: "memory")

__global__ __launch_bounds__(512, 2)
void gemm256_kernel(const ushort* __restrict__ A, const ushort* __restrict__ W,
                    const float* __restrict__ bias, ushort* __restrict__ C,
                    int K, int V)
{
    __shared__ ushort sh[65536];   // 128 KiB

    const int tid  = threadIdx.x;
    const int lane = tid & 63;
    const int wave = tid >> 6;
    const int wm = wave >> 2;      // 0..1
    const int wn = wave & 3;       // 0..3

    const int cpx = gridDim.x >> 3;
    const int wg  = ((int)blockIdx.x & 7) * cpx + ((int)blockIdx.x >> 3);
    const int row0 = (wg & 7) * 256;
    const int col0 = (wg >> 3) * 256;

    const int NT = K >> 6;
    const int NI = NT >> 1;

    const int sr = lane >> 3;
    const int sc = ((lane & 7) ^ sr) * 8;
    const size_t a_off = (size_t)(row0 + wave * 8 + sr) * K + sc;
    const size_t w_off = (size_t)(col0 + wave * 8 + sr) * K + sc;
    const int lds_u = wave * 8 * 64;

    auto stage_half = [&](const ushort* gb, size_t goff, int seg, int h, int k0) {
        const ushort* g0 = gb + goff + (size_t)(h * 128) * K + k0;
        load_lds_16B(g0,                   &sh[seg + (h * 128     ) * 64 + lds_u]);
        load_lds_16B(g0 + (size_t)64 * K,  &sh[seg + (h * 128 + 64) * 64 + lds_u]);
    };

    const int l15  = lane & 15;
    const int c16a = (((lane >> 4)    ) ^ (lane & 7)) * 8;
    const int c16b = (((lane >> 4) + 4) ^ (lane & 7)) * 8;
    const int arow = (wm * 128 + l15) * 64;
    const int brow = (wn * 64  + l15) * 64;

    f32x4 acc[8][4];
#pragma unroll
    for (int m = 0; m < 8; ++m)
#pragma unroll
        for (int n = 0; n < 4; ++n)
            acc[m][n] = (f32x4)(0.0f);

    short8v bfr[4][2];
    short8v af[2][2];

    // ---- prologue
    stage_half(A, a_off, SEG_A0, 0, 0);
    stage_half(A, a_off, SEG_A0, 1, 0);
    stage_half(W, w_off, SEG_B0, 0, 0);
    stage_half(W, w_off, SEG_B0, 1, 0);
    stage_half(W, w_off, SEG_B1, 0, 64);
    stage_half(W, w_off, SEG_B1, 1, 64);
    VMCNT4();
    BAR();

    // ---- main loop
    for (int i = 0; i < NI - 1; ++i) {
        const int kA1 = (2 * i + 1) * 64;
        const int kN2 = (2 * i + 2) * 64;
        const int kB3 = (2 * i + 3) * 64;

        READ_B_ALL(SEG_B0); READ_A2(SEG_A0, 0);
        stage_half(A, a_off, SEG_A1, 0, kA1);
        BAR(); MFMA16(0); BAR();

        READ_A2(SEG_A0, 2);
        stage_half(A, a_off, SEG_A1, 1, kA1);
        BAR(); MFMA16(2); BAR();

        READ_A2(SEG_A0, 4);
        stage_half(W, w_off, SEG_B0, 0, kN2);
        BAR(); MFMA16(4); BAR();

        READ_A2(SEG_A0, 6);
        stage_half(W, w_off, SEG_B0, 1, kN2);
        BAR(); MFMA16(6);
        VMCNT4();
        BAR();

        READ_B_ALL(SEG_B1); READ_A2(SEG_A1, 0);
        stage_half(A, a_off, SEG_A0, 0, kN2);
        BAR(); MFMA16(0); BAR();

        READ_A2(SEG_A1, 2);
        stage_half(A, a_off, SEG_A0, 1, kN2);
        BAR(); MFMA16(2); BAR();

        READ_A2(SEG_A1, 4);
        stage_half(W, w_off, SEG_B1, 0, kB3);
        BAR(); MFMA16(4); BAR();

        READ_A2(SEG_A1, 6);
        stage_half(W, w_off, SEG_B1, 1, kB3);
        BAR(); MFMA16(6);
        VMCNT4();
        BAR();
    }

    // ---- tail iter (tiles NT-2, NT-1)
    {
        const int kA1 = (NT - 1) * 64;
        READ_B_ALL(SEG_B0); READ_A2(SEG_A0, 0);
        stage_half(A, a_off, SEG_A1, 0, kA1);
        BAR(); MFMA16(0); BAR();
        READ_A2(SEG_A0, 2);
        stage_half(A, a_off, SEG_A1, 1, kA1);
        BAR(); MFMA16(2); BAR();
        READ_A2(SEG_A0, 4); BAR(); MFMA16(4); BAR();
        READ_A2(SEG_A0, 6); BAR(); MFMA16(6);
        VMCNT0();
        BAR();
        READ_B_ALL(SEG_B1); READ_A2(SEG_A1, 0); BAR(); MFMA16(0); BAR();
        READ_A2(SEG_A1, 2); BAR(); MFMA16(2); BAR();
        READ_A2(SEG_A1, 4); BAR(); MFMA16(4); BAR();
        READ_A2(SEG_A1, 6); BAR(); MFMA16(6);
    }

    // ---- epilogue: acc -> bf16 LDS tile (swizzled) -> coalesced global stores
    float bb[4];
#pragma unroll
    for (int nf = 0; nf < 4; ++nf)
        bb[nf] = bias[col0 + wn * 64 + nf * 16 + l15];

    __syncthreads();   // all ds_reads consumed (vmcnt 0): sh reusable
#pragma unroll
    for (int mf = 0; mf < 8; ++mf) {
        const int rl = wm * 128 + mf * 16 + (lane >> 4) * 4;
#pragma unroll
        for (int nf = 0; nf < 4; ++nf) {
            const int cl = wn * 64 + nf * 16 + l15;
#pragma unroll
            for (int j = 0; j < 4; ++j) {
                const int row = rl + j;
                const int pc = (((cl >> 3) ^ (((row >> 2) & 3) << 1)) << 3) + (cl & 7);
                sh[row * 256 + pc] = (ushort)f2bf(acc[mf][nf][j] + bb[nf]);
            }
        }
    }
    __syncthreads();
#pragma unroll
    for (int pass = 0; pass < 16; ++pass) {
        const int r = pass * 16 + (tid >> 5);
        const int pc16 = (tid & 31) ^ (((r >> 2) & 3) << 1);
        *reinterpret_cast<short8v*>(&C[(size_t)(row0 + r) * V + col0 + (tid & 31) * 8]) =
            *reinterpret_cast<const short8v*>(&sh[r * 256 + pc16 * 8]);
    }
}

// ---------------- fused row stats + loss, register-resident (bf16 logits) ----------------
// Each thread holds its 4x short8v of S and T across both passes (no refetch).
__global__ __launch_bounds__(1024)
void stats_loss_kernel(const ushort* __restrict__ S, const ushort* __restrict__ Tm,
                       const int* __restrict__ tgt, double* __restrict__ accum, int V)
{
    const int r = blockIdx.x;
    const ushort* s = S  + (size_t)r * V;
    const ushort* t = Tm + (size_t)r * V;
    const int tid = threadIdx.x;

    short8v sv[4], tv[4];
    bool valid[4];

    // pass 1: per-row online stats.
    // e = exp((x-m)/2): lh += e (T=2 sum), l1 += e*e (T=1 sum). One exp serves both.
    float ms = -1e30f, l1 = 0.f, lh = 0.f;
    float mt = -1e30f, lt = 0.f;
#pragma unroll
    for (int it = 0; it < 4; ++it) {
        const int v = it * 8192 + tid * 8;
        valid[it] = (v < V);
        if (valid[it]) {
            sv[it] = *reinterpret_cast<const short8v*>(&s[v]);
            tv[it] = *reinterpret_cast<const short8v*>(&t[v]);
#pragma unroll
            for (int j = 0; j < 8; ++j) {
                float x = bf2f((ushort)sv[it][j]);
                if (x > ms) {
                    float eh = __expf(0.5f * (ms - x));
                    lh *= eh; l1 *= eh * eh; ms = x;
                }
                float e = __expf(0.5f * (x - ms));
                lh += e; l1 += e * e;
                float y = bf2f((ushort)tv[it][j]);
                if (y > mt) {
                    lt *= __expf(0.5f * (mt - y));
                    mt = y;
                }
                lt += __expf(0.5f * (y - mt));
            }
        }
    }
#pragma unroll
    for (int off = 32; off > 0; off >>= 1) {
        float mso = __shfl_xor(ms, off), l1o = __shfl_xor(l1, off), lho = __shfl_xor(lh, off);
        float mn = fmaxf(ms, mso);
        float ea = __expf(0.5f * (ms - mn)), eb = __expf(0.5f * (mso - mn));
        lh = lh * ea + lho * eb;
        l1 = l1 * ea * ea + l1o * eb * eb;
        ms = mn;
        float mto = __shfl_xor(mt, off), lto = __shfl_xor(lt, off);
        float mn2 = fmaxf(mt, mto);
        lt = lt * __expf(0.5f * (mt - mn2)) + lto * __expf(0.5f * (mto - mn2));
        mt = mn2;
    }
    __shared__ float red[16][5];
    __shared__ float bc[3];
    if ((tid & 63) == 0) {
        int w = tid >> 6;
        red[w][0] = ms; red[w][1] = l1; red[w][2] = lh;
        red[w][3] = mt; red[w][4] = lt;
    }
    __syncthreads();
    if (tid == 0) {
        float M = red[0][0], L1 = red[0][1], LH = red[0][2];
        float Mt = red[0][3], Lt = red[0][4];
#pragma unroll
        for (int w = 1; w < 16; ++w) {
            float mn = fmaxf(M, red[w][0]);
            float ea = __expf(0.5f * (M - mn)), eb = __expf(0.5f * (red[w][0] - mn));
            LH = LH * ea + red[w][2] * eb;
            L1 = L1 * ea * ea + red[w][1] * eb * eb;
            M = mn;
            float mn2 = fmaxf(Mt, red[w][3]);
            Lt = Lt * __expf(0.5f * (Mt - mn2)) + red[w][4] * __expf(0.5f * (red[w][3] - mn2));
            Mt = mn2;
        }
        bc[0] = M + __logf(L1);             // lse_s (T=1)
        bc[1] = 0.5f * M + __logf(LH);      // lse_s (T=2)
        bc[2] = 0.5f * Mt + __logf(Lt);     // lse_t (T=2)
    }
    __syncthreads();
    const float ls1 = bc[0], ls2 = bc[1], lt2 = bc[2];

    // pass 2: JSD from register-resident values
    float local = 0.f;
#pragma unroll
    for (int it = 0; it < 4; ++it) {
        if (valid[it]) {
#pragma unroll
            for (int j = 0; j < 8; ++j) {
                float sp = 0.5f * bf2f((ushort)sv[it][j]) - ls2;
                float tp = 0.5f * bf2f((ushort)tv[it][j]) - lt2;
                float p = __expf(sp), q = __expf(tp);
                float mm = 0.5f * (p + q);
                float lm = __logf(fmaxf(mm, 1e-38f));
                local += 0.5f * (p * (sp - lm) + q * (tp - lm));
            }
        }
    }
#pragma unroll
    for (int off = 32; off > 0; off >>= 1)
        local += __shfl_xor(local, off);
    __shared__ float ls[16];
    if ((tid & 63) == 0) ls[tid >> 6] = local;
    __syncthreads();
    if (tid == 0) {
        float blocksum = 0.f;
#pragma unroll
        for (int w = 0; w < 16; ++w) blocksum += ls[w];
        atomicAdd(&accum[1], (double)blocksum);
        int tg = tgt[r];
        if (tg != -100) {
            float nll = -(bf2f(s[tg]) - ls1);
            atomicAdd(&accum[0], (double)nll);
        }
    }
}

__global__ void finalize_kernel(const double* __restrict__ accum,
                                float* __restrict__ out, double inv_n) {
    out[0] = (float)(0.5 * (accum[0] * inv_n) + 0.5 * (accum[1] * inv_n));
}

extern "C" void kernel_launch(void* const* d_in, const int* in_sizes, int n_in,
                              void* d_out, int out_size, void* d_ws, size_t ws_size,
                              hipStream_t stream)
{
    const float* s_in = (const float*)d_in[0];   // [N, 2048]
    const float* s_w  = (const float*)d_in[1];   // [V, 2048]
    const float* s_b  = (const float*)d_in[2];   // [V]
    const float* t_in = (const float*)d_in[3];   // [N, 4096]
    const float* t_w  = (const float*)d_in[4];   // [V, 4096]
    const float* t_b  = (const float*)d_in[5];   // [V]
    const int*   tgt  = (const int*)d_in[6];     // [N]

    const int N = 2048, V = 32000, KS = 2048, KT = 4096;

    const size_t e_sin = (size_t)N * KS;
    const size_t e_sw  = (size_t)V * KS;
    const size_t e_tin = (size_t)N * KT;
    const size_t e_tw  = (size_t)V * KT;
    const size_t bf16_bytes = 2 * (e_sin + e_sw + e_tin + e_tw);   // 418,381,824

    char* ws = (char*)d_ws;
    double* accum = (double*)ws;

    ushort* s_in_b = (ushort*)(ws + 4096);
    ushort* s_w_b  = s_in_b + e_sin;
    ushort* t_in_b = s_w_b + e_sw;
    ushort* t_w_b  = t_in_b + e_tin;
    ushort* s_log  = (ushort*)(ws + 4096 + bf16_bytes);
    ushort* t_log  = s_log + (size_t)N * V;

    // fused convert (+ accum zero): dst regions contiguous starting at s_in_b
    const size_t c0 = e_sin / 8;
    const size_t c1 = c0 + e_sw / 8;
    const size_t c2 = c1 + e_tin / 8;
    const size_t c3 = c2 + e_tw / 8;
    cvt4_kernel<<<2048, 256, 0, stream>>>(s_in, s_w, t_in, t_w, s_in_b, accum, c0, c1, c2, c3);

    const int grid = (V / 256) * (N / 256);   // 125 * 8 = 1000, %8==0
    gemm256_kernel<<<grid, 512, 0, stream>>>(s_in_b, s_w_b, s_b, s_log, KS, V);
    gemm256_kernel<<<grid, 512, 0, stream>>>(t_in_b, t_w_b, t_b, t_log, KT, V);

    stats_loss_kernel<<<N, 1024, 0, stream>>>(s_log, t_log, tgt, accum, V);

    finalize_kernel<<<1, 1, 0, stream>>>(accum, (float*)d_out, 1.0 / (double)N);
}

// Round 6
// 721.231 us; speedup vs baseline: 1.4530x; 1.4530x over previous
//
#include <hip/hip_runtime.h>
#include <hip/hip_bf16.h>
#include <cstdint>
#include <cstddef>

typedef __attribute__((ext_vector_type(8))) short short8v;
typedef __attribute__((ext_vector_type(4))) int   i32x4;

__device__ __forceinline__ short f2bf(float f) {
    union { float f; unsigned u; } c; c.f = f;
    unsigned r = c.u + 0x7FFFu + ((c.u >> 16) & 1u);
    return (short)(r >> 16);
}

__device__ __forceinline__ float bf2f(ushort u) {
    union { unsigned u; float f; } c; c.u = ((unsigned)u) << 16;
    return c.f;
}

__device__ __forceinline__ void load_lds_16B(const void* g, void* l) {
    __builtin_amdgcn_global_load_lds(
        (const __attribute__((address_space(1))) void*)g,
        (__attribute__((address_space(3))) void*)l, 16, 0, 0);
}

// ---------------- per-row symmetric int8 quantization ----------------
// One block per row. R in {2048, 4096}. Interleaved float4 chunks: thread tid
// covers elements g*1024 + tid*4. Scale = absmax/127; values clamped +-127.
__global__ __launch_bounds__(256)
void quant_kernel(const float* __restrict__ src, uint8_t* __restrict__ dst,
                  float* __restrict__ scales, int R, double* accum)
{
    if (accum && blockIdx.x == 0 && threadIdx.x == 0) { accum[0] = 0.0; accum[1] = 0.0; }
    const int r = blockIdx.x;
    const int tid = threadIdx.x;
    const float* x = src + (size_t)r * R;
    const int ng = R >> 10;          // 2 or 4

    float4 v[4];
    float am = 0.f;
#pragma unroll
    for (int g = 0; g < 4; ++g) {
        if (g < ng) {
            v[g] = *reinterpret_cast<const float4*>(&x[g * 1024 + tid * 4]);
            am = fmaxf(am, fmaxf(fmaxf(fabsf(v[g].x), fabsf(v[g].y)),
                                 fmaxf(fabsf(v[g].z), fabsf(v[g].w))));
        }
    }
#pragma unroll
    for (int off = 32; off > 0; off >>= 1)
        am = fmaxf(am, __shfl_xor(am, off));
    __shared__ float wam[4];
    if ((tid & 63) == 0) wam[tid >> 6] = am;
    __syncthreads();
    am = fmaxf(fmaxf(wam[0], wam[1]), fmaxf(wam[2], wam[3]));
    am = fmaxf(am, 1e-20f);
    const float inv = 127.0f / am;
    if (tid == 0) scales[r] = am / 127.0f;

    uint32_t* out = (uint32_t*)(dst + (size_t)r * R);
#pragma unroll
    for (int g = 0; g < 4; ++g) {
        if (g < ng) {
            int q0 = __float2int_rn(v[g].x * inv);
            int q1 = __float2int_rn(v[g].y * inv);
            int q2 = __float2int_rn(v[g].z * inv);
            int q3 = __float2int_rn(v[g].w * inv);
            q0 = min(127, max(-127, q0)); q1 = min(127, max(-127, q1));
            q2 = min(127, max(-127, q2)); q3 = min(127, max(-127, q3));
            uint32_t pack = (q0 & 255) | ((q1 & 255) << 8) | ((q2 & 255) << 16) | ((uint32_t)(q3 & 255) << 24);
            out[g * 256 + tid] = pack;
        }
    }
}

// ---------------- 256x256 8-phase int8 GEMM (T1+T2+T3+T4+T5), bf16 C ----------------
// Byte-identical structure to the verified bf16 kernel: 32KB segments, 128B rows
// (8 x 16B blocks), inverse-swizzled global sources, linear LDS dest, XOR'd
// ds_reads, 2 gload_lds staged per phase, vmcnt(4) at ph4/ph8. Only change:
// elements are i8 so one K-tile covers K=128 and each MFMA is 16x16x64 i8.
// C[row,col] = bf16( sa[row]*sw[col]*idot + bias[col] ).

#define SEG_A0 0
#define SEG_A1 32768
#define SEG_B0 65536
#define SEG_B1 98304

#define READ_B_ALL(bseg) do {                                                  \
    _Pragma("unroll")                                                          \
    for (int nf = 0; nf < 4; ++nf) {                                           \
        const int rb = (bseg) + brow + nf * 2048;                              \
        bfr[nf][0] = *(const i32x4*)&sh[rb + c16a];                            \
        bfr[nf][1] = *(const i32x4*)&sh[rb + c16b];                            \
    }                                                                          \
} while (0)

#define READ_A2(aseg, mfb) do {                                                \
    _Pragma("unroll")                                                          \
    for (int d = 0; d < 2; ++d) {                                              \
        const int ra = (aseg) + arow + ((mfb) + d) * 2048;                     \
        af[d][0] = *(const i32x4*)&sh[ra + c16a];                              \
        af[d][1] = *(const i32x4*)&sh[ra + c16b];                              \
    }                                                                          \
} while (0)

#define MFMA16(mfb) do {                                                       \
    __builtin_amdgcn_s_setprio(1);                                             \
    _Pragma("unroll")                                                          \
    for (int d = 0; d < 2; ++d) {                                              \
        _Pragma("unroll")                                                      \
        for (int nf = 0; nf < 4; ++nf) {                                       \
            acc[(mfb)+d][nf] = __builtin_amdgcn_mfma_i32_16x16x64_i8(          \
                af[d][0], bfr[nf][0], acc[(mfb)+d][nf], 0, 0, 0);              \
            acc[(mfb)+d][nf] = __builtin_amdgcn_mfma_i32_16x16x64_i8(          \
                af[d][1], bfr[nf][1], acc[(mfb)+d][nf], 0, 0, 0);              \
        }                                                                      \
    }                                                                          \
    __builtin_amdgcn_s_setprio(0);                                             \
} while (0)

#define BAR() __builtin_amdgcn_s_barrier()
#define VMCNT4() asm volatile("s_waitcnt vmcnt(4)" ::: "memory")
#define VMCNT0() asm volatile("s_waitcnt vmcnt(0)" ::: "memory")

__global__ __launch_bounds__(512, 2)
void gemm256_i8_kernel(const uint8_t* __restrict__ A, const uint8_t* __restrict__ W,
                       const float* __restrict__ sa, const float* __restrict__ sw,
                       const float* __restrict__ bias, ushort* __restrict__ C,
                       int K, int V)
{
    __shared__ uint8_t sh[131072];   // 128 KiB
    ushort* shs = (ushort*)sh;

    const int tid  = threadIdx.x;
    const int lane = tid & 63;
    const int wave = tid >> 6;
    const int wm = wave >> 2;      // 0..1
    const int wn = wave & 3;       // 0..3

    const int cpx = gridDim.x >> 3;
    const int wg  = ((int)blockIdx.x & 7) * cpx + ((int)blockIdx.x >> 3);
    const int row0 = (wg & 7) * 256;
    const int col0 = (wg >> 3) * 256;

    const int NT = K >> 7;         // K-tiles of 128 i8
    const int NI = NT >> 1;

    const int sr  = lane >> 3;
    const int scb = ((lane & 7) ^ sr) * 16;     // byte (=element) offset, inverse swizzle
    const size_t a_off = (size_t)(row0 + wave * 8 + sr) * K + scb;
    const size_t w_off = (size_t)(col0 + wave * 8 + sr) * K + scb;
    const int lds_u = wave * 1024;              // wave*8 rows * 128 B

    auto stage_half = [&](const uint8_t* gb, size_t goff, int seg, int h, int k0) {
        const uint8_t* g0 = gb + goff + (size_t)(h * 128) * K + k0;
        load_lds_16B(g0,                  &sh[seg + h * 16384 + lds_u]);
        load_lds_16B(g0 + (size_t)64 * K, &sh[seg + h * 16384 + 8192 + lds_u]);
    };

    const int l15  = lane & 15;
    const int c16a = (((lane >> 4)    ) ^ (lane & 7)) * 16;   // bytes
    const int c16b = (((lane >> 4) + 4) ^ (lane & 7)) * 16;
    const int arow = (wm * 128 + l15) * 128;                  // bytes
    const int brow = (wn * 64  + l15) * 128;

    i32x4 acc[8][4];
#pragma unroll
    for (int m = 0; m < 8; ++m)
#pragma unroll
        for (int n = 0; n < 4; ++n)
            acc[m][n] = (i32x4)(0);

    i32x4 bfr[4][2];
    i32x4 af[2][2];

    // ---- prologue
    stage_half(A, a_off, SEG_A0, 0, 0);
    stage_half(A, a_off, SEG_A0, 1, 0);
    stage_half(W, w_off, SEG_B0, 0, 0);
    stage_half(W, w_off, SEG_B0, 1, 0);
    stage_half(W, w_off, SEG_B1, 0, 128);
    stage_half(W, w_off, SEG_B1, 1, 128);
    VMCNT4();
    BAR();

    // ---- main loop
    for (int i = 0; i < NI - 1; ++i) {
        const int kA1 = (2 * i + 1) * 128;
        const int kN2 = (2 * i + 2) * 128;
        const int kB3 = (2 * i + 3) * 128;

        READ_B_ALL(SEG_B0); READ_A2(SEG_A0, 0);
        stage_half(A, a_off, SEG_A1, 0, kA1);
        BAR(); MFMA16(0); BAR();

        READ_A2(SEG_A0, 2);
        stage_half(A, a_off, SEG_A1, 1, kA1);
        BAR(); MFMA16(2); BAR();

        READ_A2(SEG_A0, 4);
        stage_half(W, w_off, SEG_B0, 0, kN2);
        BAR(); MFMA16(4); BAR();

        READ_A2(SEG_A0, 6);
        stage_half(W, w_off, SEG_B0, 1, kN2);
        BAR(); MFMA16(6);
        VMCNT4();
        BAR();

        READ_B_ALL(SEG_B1); READ_A2(SEG_A1, 0);
        stage_half(A, a_off, SEG_A0, 0, kN2);
        BAR(); MFMA16(0); BAR();

        READ_A2(SEG_A1, 2);
        stage_half(A, a_off, SEG_A0, 1, kN2);
        BAR(); MFMA16(2); BAR();

        READ_A2(SEG_A1, 4);
        stage_half(W, w_off, SEG_B1, 0, kB3);
        BAR(); MFMA16(4); BAR();

        READ_A2(SEG_A1, 6);
        stage_half(W, w_off, SEG_B1, 1, kB3);
        BAR(); MFMA16(6);
        VMCNT4();
        BAR();
    }

    // ---- tail iter (tiles NT-2, NT-1)
    {
        const int kA1 = (NT - 1) * 128;
        READ_B_ALL(SEG_B0); READ_A2(SEG_A0, 0);
        stage_half(A, a_off, SEG_A1, 0, kA1);
        BAR(); MFMA16(0); BAR();
        READ_A2(SEG_A0, 2);
        stage_half(A, a_off, SEG_A1, 1, kA1);
        BAR(); MFMA16(2); BAR();
        READ_A2(SEG_A0, 4); BAR(); MFMA16(4); BAR();
        READ_A2(SEG_A0, 6); BAR(); MFMA16(6);
        VMCNT0();
        BAR();
        READ_B_ALL(SEG_B1); READ_A2(SEG_A1, 0); BAR(); MFMA16(0); BAR();
        READ_A2(SEG_A1, 2); BAR(); MFMA16(2); BAR();
        READ_A2(SEG_A1, 4); BAR(); MFMA16(4); BAR();
        READ_A2(SEG_A1, 6); BAR(); MFMA16(6);
    }

    // ---- epilogue: dequant + bias -> bf16 LDS tile (swizzled) -> coalesced stores
    float bb[4], swv[4];
#pragma unroll
    for (int nf = 0; nf < 4; ++nf) {
        const int gc = col0 + wn * 64 + nf * 16 + l15;
        bb[nf]  = bias[gc];
        swv[nf] = sw[gc];
    }

    __syncthreads();   // all ds_reads consumed (vmcnt 0): sh reusable
#pragma unroll
    for (int mf = 0; mf < 8; ++mf) {
        const int rl = wm * 128 + mf * 16 + (lane >> 4) * 4;
        const float4 sav = *reinterpret_cast<const float4*>(&sa[row0 + rl]);
        const float* savp = (const float*)&sav;
#pragma unroll
        for (int nf = 0; nf < 4; ++nf) {
            const int cl = wn * 64 + nf * 16 + l15;
#pragma unroll
            for (int j = 0; j < 4; ++j) {
                const int row = rl + j;
                const float v = (float)acc[mf][nf][j] * (savp[j] * swv[nf]) + bb[nf];
                const int pc = (((cl >> 3) ^ (((row >> 2) & 3) << 1)) << 3) + (cl & 7);
                shs[row * 256 + pc] = (ushort)f2bf(v);
            }
        }
    }
    __syncthreads();
#pragma unroll
    for (int pass = 0; pass < 16; ++pass) {
        const int r = pass * 16 + (tid >> 5);
        const int pc16 = (tid & 31) ^ (((r >> 2) & 3) << 1);
        *reinterpret_cast<short8v*>(&C[(size_t)(row0 + r) * V + col0 + (tid & 31) * 8]) =
            *reinterpret_cast<const short8v*>(&shs[r * 256 + pc16 * 8]);
    }
}

// ---------------- fused row stats + loss, register-resident (bf16 logits) ----------------
__global__ __launch_bounds__(1024)
void stats_loss_kernel(const ushort* __restrict__ S, const ushort* __restrict__ Tm,
                       const int* __restrict__ tgt, double* __restrict__ accum, int V)
{
    const int r = blockIdx.x;
    const ushort* s = S  + (size_t)r * V;
    const ushort* t = Tm + (size_t)r * V;
    const int tid = threadIdx.x;

    short8v sv[4], tv[4];
    bool valid[4];

    // pass 1: e = exp((x-m)/2): lh += e (T=2 sum), l1 += e*e (T=1 sum).
    float ms = -1e30f, l1 = 0.f, lh = 0.f;
    float mt = -1e30f, lt = 0.f;
#pragma unroll
    for (int it = 0; it < 4; ++it) {
        const int v = it * 8192 + tid * 8;
        valid[it] = (v < V);
        if (valid[it]) {
            sv[it] = *reinterpret_cast<const short8v*>(&s[v]);
            tv[it] = *reinterpret_cast<const short8v*>(&t[v]);
#pragma unroll
            for (int j = 0; j < 8; ++j) {
                float x = bf2f((ushort)sv[it][j]);
                if (x > ms) {
                    float eh = __expf(0.5f * (ms - x));
                    lh *= eh; l1 *= eh * eh; ms = x;
                }
                float e = __expf(0.5f * (x - ms));
                lh += e; l1 += e * e;
                float y = bf2f((ushort)tv[it][j]);
                if (y > mt) {
                    lt *= __expf(0.5f * (mt - y));
                    mt = y;
                }
                lt += __expf(0.5f * (y - mt));
            }
        }
    }
#pragma unroll
    for (int off = 32; off > 0; off >>= 1) {
        float mso = __shfl_xor(ms, off), l1o = __shfl_xor(l1, off), lho = __shfl_xor(lh, off);
        float mn = fmaxf(ms, mso);
        float ea = __expf(0.5f * (ms - mn)), eb = __expf(0.5f * (mso - mn));
        lh = lh * ea + lho * eb;
        l1 = l1 * ea * ea + l1o * eb * eb;
        ms = mn;
        float mto = __shfl_xor(mt, off), lto = __shfl_xor(lt, off);
        float mn2 = fmaxf(mt, mto);
        lt = lt * __expf(0.5f * (mt - mn2)) + lto * __expf(0.5f * (mto - mn2));
        mt = mn2;
    }
    __shared__ float red[16][5];
    __shared__ float bc[3];
    if ((tid & 63) == 0) {
        int w = tid >> 6;
        red[w][0] = ms; red[w][1] = l1; red[w][2] = lh;
        red[w][3] = mt; red[w][4] = lt;
    }
    __syncthreads();
    if (tid == 0) {
        float M = red[0][0], L1 = red[0][1], LH = red[0][2];
        float Mt = red[0][3], Lt = red[0][4];
#pragma unroll
        for (int w = 1; w < 16; ++w) {
            float mn = fmaxf(M, red[w][0]);
            float ea = __expf(0.5f * (M - mn)), eb = __expf(0.5f * (red[w][0] - mn));
            LH = LH * ea + red[w][2] * eb;
            L1 = L1 * ea * ea + red[w][1] * eb * eb;
            M = mn;
            float mn2 = fmaxf(Mt, red[w][3]);
            Lt = Lt * __expf(0.5f * (Mt - mn2)) + red[w][4] * __expf(0.5f * (red[w][3] - mn2));
            Mt = mn2;
        }
        bc[0] = M + __logf(L1);             // lse_s (T=1)
        bc[1] = 0.5f * M + __logf(LH);      // lse_s (T=2)
        bc[2] = 0.5f * Mt + __logf(Lt);     // lse_t (T=2)
    }
    __syncthreads();
    const float ls1 = bc[0], ls2 = bc[1], lt2 = bc[2];

    // pass 2: JSD from register-resident values
    float local = 0.f;
#pragma unroll
    for (int it = 0; it < 4; ++it) {
        if (valid[it]) {
#pragma unroll
            for (int j = 0; j < 8; ++j) {
                float sp = 0.5f * bf2f((ushort)sv[it][j]) - ls2;
                float tp = 0.5f * bf2f((ushort)tv[it][j]) - lt2;
                float p = __expf(sp), q = __expf(tp);
                float mm = 0.5f * (p + q);
                float lm = __logf(fmaxf(mm, 1e-38f));
                local += 0.5f * (p * (sp - lm) + q * (tp - lm));
            }
        }
    }
#pragma unroll
    for (int off = 32; off > 0; off >>= 1)
        local += __shfl_xor(local, off);
    __shared__ float ls[16];
    if ((tid & 63) == 0) ls[tid >> 6] = local;
    __syncthreads();
    if (tid == 0) {
        float blocksum = 0.f;
#pragma unroll
        for (int w = 0; w < 16; ++w) blocksum += ls[w];
        atomicAdd(&accum[1], (double)blocksum);
        int tg = tgt[r];
        if (tg != -100) {
            float nll = -(bf2f(s[tg]) - ls1);
            atomicAdd(&accum[0], (double)nll);
        }
    }
}

__global__ void finalize_kernel(const double* __restrict__ accum,
                                float* __restrict__ out, double inv_n) {
    out[0] = (float)(0.5 * (accum[0] * inv_n) + 0.5 * (accum[1] * inv_n));
}

extern "C" void kernel_launch(void* const* d_in, const int* in_sizes, int n_in,
                              void* d_out, int out_size, void* d_ws, size_t ws_size,
                              hipStream_t stream)
{
    const float* s_in = (const float*)d_in[0];   // [N, 2048]
    const float* s_w  = (const float*)d_in[1];   // [V, 2048]
    const float* s_b  = (const float*)d_in[2];   // [V]
    const float* t_in = (const float*)d_in[3];   // [N, 4096]
    const float* t_w  = (const float*)d_in[4];   // [V, 4096]
    const float* t_b  = (const float*)d_in[5];   // [V]
    const int*   tgt  = (const int*)d_in[6];     // [N]

    const int N = 2048, V = 32000, KS = 2048, KT = 4096;

    const size_t e_sin = (size_t)N * KS;          // 4,194,304
    const size_t e_sw  = (size_t)V * KS;          // 65,536,000
    const size_t e_tin = (size_t)N * KT;          // 8,388,608
    const size_t e_tw  = (size_t)V * KT;          // 131,072,000

    char* ws = (char*)d_ws;
    double* accum = (double*)ws;

    // scale arrays
    float* sa_s = (float*)(ws + 4096);            // 2048
    float* sa_t = sa_s + 2048;                    // 2048
    float* sw_s = sa_t + 2048;                    // 32000
    float* sw_t = sw_s + 32000;                   // 32000
    // int8 data (start 4096-aligned: 4096 + 272384 -> pad to 278528)
    uint8_t* s_in_q = (uint8_t*)(ws + 278528);
    uint8_t* s_w_q  = s_in_q + e_sin;
    uint8_t* t_in_q = s_w_q + e_sw;
    uint8_t* t_w_q  = t_in_q + e_tin;
    // bf16 logits
    ushort* s_log = (ushort*)(t_w_q + e_tw);
    ushort* t_log = s_log + (size_t)N * V;

    quant_kernel<<<N, 256, 0, stream>>>(s_in, s_in_q, sa_s, KS, accum);  // + zero accum
    quant_kernel<<<N, 256, 0, stream>>>(t_in, t_in_q, sa_t, KT, nullptr);
    quant_kernel<<<V, 256, 0, stream>>>(s_w, s_w_q, sw_s, KS, nullptr);
    quant_kernel<<<V, 256, 0, stream>>>(t_w, t_w_q, sw_t, KT, nullptr);

    const int grid = (V / 256) * (N / 256);   // 1000, %8==0
    gemm256_i8_kernel<<<grid, 512, 0, stream>>>(s_in_q, s_w_q, sa_s, sw_s, s_b, s_log, KS, V);
    gemm256_i8_kernel<<<grid, 512, 0, stream>>>(t_in_q, t_w_q, sa_t, sw_t, t_b, t_log, KT, V);

    stats_loss_kernel<<<N, 1024, 0, stream>>>(s_log, t_log, tgt, accum, V);

    finalize_kernel<<<1, 1, 0, stream>>>(accum, (float*)d_out, 1.0 / (double)N);
}